// Round 1
// baseline (92.494 us; speedup 1.0000x reference)
//
#include <hip/hip_runtime.h>

#define BIGV 1.0e6f

// One block per (b, h). 256 threads: w = tid&63, chunk c = tid>>6.
// Each thread scans i in [c*16, c*16+16) x j in [0,64), tracking
//   m1 = min dist * pred[b,i,j]   (for min_dist,    scaled later by gt_th)
//   m2 = min dist * gt[b,i,j]     (for min_dist_inv, scaled later by pred_th)
__global__ __launch_bounds__(256) void imageloss_main(
    const float* __restrict__ gt, const float* __restrict__ pred,
    float* __restrict__ ws)
{
    __shared__ float gt_s[4096];
    __shared__ float pr_s[4096];
    __shared__ float red1[256];
    __shared__ float red2[256];

    const int blk = blockIdx.x;        // 0..511
    const int b   = blk >> 6;
    const int h   = blk & 63;
    const int tid = threadIdx.x;

    const float* __restrict__ gt_b = gt   + b * 4096;
    const float* __restrict__ pr_b = pred + b * 4096;

    // Stage both 64x64 images to LDS: 1024 float4 each, 256 threads -> 4 apiece.
    #pragma unroll
    for (int k = 0; k < 4; ++k) {
        int idx = tid + k * 256;
        ((float4*)gt_s)[idx] = ((const float4*)gt_b)[idx];
        ((float4*)pr_s)[idx] = ((const float4*)pr_b)[idx];
    }
    __syncthreads();

    const int w = tid & 63;
    const int c = tid >> 6;
    const float wf = (float)w;

    float m1 = 3.4e38f;
    float m2 = 3.4e38f;

    for (int i = c * 16; i < c * 16 + 16; ++i) {
        const float dx  = (float)(h - i);
        const float dx2 = dx * dx;
        const float* __restrict__ pr_row = pr_s + i * 64;
        const float* __restrict__ gt_row = gt_s + i * 64;
        #pragma unroll 16
        for (int j = 0; j < 64; ++j) {
            float dy = wf - (float)j;
            float d  = sqrtf(fmaf(dy, dy, dx2)) + 1.0f;
            m1 = fminf(m1, d * pr_row[j]);   // dist * pred
            m2 = fminf(m2, d * gt_row[j]);   // dist * gt
        }
    }

    red1[tid] = m1;
    red2[tid] = m2;
    __syncthreads();

    if (tid < 64) {
        // Combine the 4 chunks for this w.
        m1 = fminf(fminf(red1[w], red1[64 + w]), fminf(red1[128 + w], red1[192 + w]));
        m2 = fminf(fminf(red2[w], red2[64 + w]), fminf(red2[128 + w], red2[192 + w]));

        const float g = gt_s[h * 64 + w];
        const float p = pr_s[h * 64 + w];
        const float gth = g + (1.0f - g) * BIGV;
        const float pth = p + (1.0f - p) * BIGV;

        float c1 = gth * m1;   // contributes to min_dist
        float c2 = pth * m2;   // contributes to min_dist_inv
        float df = g - p;
        float sq = df * df;    // contributes to loss

        // Wave reduce across the 64 lanes (tid 0..63 is one wave).
        #pragma unroll
        for (int off = 32; off > 0; off >>= 1) {
            c1 += __shfl_down(c1, off, 64);
            c2 += __shfl_down(c2, off, 64);
            sq += __shfl_down(sq, off, 64);
        }
        if (w == 0) {
            atomicAdd(&ws[0], sq);
            atomicAdd(&ws[1], c1);
            atomicAdd(&ws[2], c2);
        }
    }
}

__global__ void imageloss_final(const float* __restrict__ ws, float* __restrict__ out)
{
    // loss: mean over (B,H)=512 of per-row sums; min_dist(_inv): mean over 32768.
    out[0] = ws[0] * (1.0f / 512.0f);
    out[1] = ws[1] * (1.0f / 32768.0f);
    out[2] = ws[2] * (1.0f / 32768.0f);
}

extern "C" void kernel_launch(void* const* d_in, const int* in_sizes, int n_in,
                              void* d_out, int out_size, void* d_ws, size_t ws_size,
                              hipStream_t stream)
{
    const float* gt   = (const float*)d_in[0];
    const float* pred = (const float*)d_in[1];
    float* out = (float*)d_out;
    float* ws  = (float*)d_ws;

    hipMemsetAsync(ws, 0, 3 * sizeof(float), stream);
    imageloss_main<<<512, 256, 0, stream>>>(gt, pred, ws);
    imageloss_final<<<1, 1, 0, stream>>>(ws, out);
}

// Round 2
// 46.750 us; speedup vs baseline: 1.9785x; 1.9785x over previous
//
#include <hip/hip_runtime.h>

#define BIGV 1.0e6f

// One block per (b, h). 256 threads: w = tid&63, chunk c = tid>>6.
// Each thread scans i in [c*16, c*16+16) x j in [0,64), tracking
//   m1 = min (d+1) * pred[b,i,j]   (for min_dist,     scaled later by gt_th)
//   m2 = min (d+1) * gt[b,i,j]     (for min_dist_inv, scaled later by pred_th)
// using (d+1)*p = fma(d, p, p) and raw v_sqrt_f32.
__global__ __launch_bounds__(256) void imageloss_main(
    const float* __restrict__ gt, const float* __restrict__ pred,
    float* __restrict__ ws)
{
    __shared__ float gt_s[4096];
    __shared__ float pr_s[4096];
    __shared__ float red1[256];
    __shared__ float red2[256];

    const int blk = blockIdx.x;        // 0..511
    const int b   = blk >> 6;
    const int h   = blk & 63;
    const int tid = threadIdx.x;

    const float* __restrict__ gt_b = gt   + b * 4096;
    const float* __restrict__ pr_b = pred + b * 4096;

    // Stage both 64x64 images to LDS: 1024 float4 each, 256 threads -> 4 apiece.
    #pragma unroll
    for (int k = 0; k < 4; ++k) {
        int idx = tid + k * 256;
        ((float4*)gt_s)[idx] = ((const float4*)gt_b)[idx];
        ((float4*)pr_s)[idx] = ((const float4*)pr_b)[idx];
    }
    __syncthreads();

    const int w = tid & 63;
    const int c = tid >> 6;
    const float wf = (float)w;

    float m1 = 3.4e38f;
    float m2 = 3.4e38f;

    for (int i = c * 16; i < c * 16 + 16; ++i) {
        const float dxf = (float)(h - i);
        const float dx2 = dxf * dxf;
        const float4* __restrict__ pr4 = (const float4*)(pr_s + i * 64);
        const float4* __restrict__ gt4 = (const float4*)(gt_s + i * 64);
        #pragma unroll
        for (int j4 = 0; j4 < 16; ++j4) {
            float4 p4 = pr4[j4];   // uniform address -> ds_read_b128 broadcast
            float4 g4 = gt4[j4];
            #pragma unroll
            for (int t = 0; t < 4; ++t) {
                float jf = (float)(j4 * 4 + t);          // literal after unroll
                float dy = wf - jf;
                float d  = __builtin_amdgcn_sqrtf(fmaf(dy, dy, dx2)); // v_sqrt_f32
                float p  = (&p4.x)[t];
                float g  = (&g4.x)[t];
                m1 = fminf(m1, fmaf(d, p, p));   // (d+1)*p
                m2 = fminf(m2, fmaf(d, g, g));   // (d+1)*g
            }
        }
    }

    red1[tid] = m1;
    red2[tid] = m2;
    __syncthreads();

    if (tid < 64) {
        // Combine the 4 chunks for this w.
        m1 = fminf(fminf(red1[w], red1[64 + w]), fminf(red1[128 + w], red1[192 + w]));
        m2 = fminf(fminf(red2[w], red2[64 + w]), fminf(red2[128 + w], red2[192 + w]));

        const float g = gt_s[h * 64 + w];
        const float p = pr_s[h * 64 + w];
        const float gth = g + (1.0f - g) * BIGV;
        const float pth = p + (1.0f - p) * BIGV;

        float c1 = gth * m1;   // contributes to min_dist
        float c2 = pth * m2;   // contributes to min_dist_inv
        float df = g - p;
        float sq = df * df;    // contributes to loss

        // Wave reduce across the 64 lanes (tid 0..63 is one wave).
        #pragma unroll
        for (int off = 32; off > 0; off >>= 1) {
            c1 += __shfl_down(c1, off, 64);
            c2 += __shfl_down(c2, off, 64);
            sq += __shfl_down(sq, off, 64);
        }
        if (w == 0) {
            atomicAdd(&ws[0], sq);
            atomicAdd(&ws[1], c1);
            atomicAdd(&ws[2], c2);
        }
    }
}

__global__ void imageloss_final(const float* __restrict__ ws, float* __restrict__ out)
{
    // loss: mean over (B,H)=512 of per-row sums; min_dist(_inv): mean over 32768.
    out[0] = ws[0] * (1.0f / 512.0f);
    out[1] = ws[1] * (1.0f / 32768.0f);
    out[2] = ws[2] * (1.0f / 32768.0f);
}

extern "C" void kernel_launch(void* const* d_in, const int* in_sizes, int n_in,
                              void* d_out, int out_size, void* d_ws, size_t ws_size,
                              hipStream_t stream)
{
    const float* gt   = (const float*)d_in[0];
    const float* pred = (const float*)d_in[1];
    float* out = (float*)d_out;
    float* ws  = (float*)d_ws;

    hipMemsetAsync(ws, 0, 3 * sizeof(float), stream);
    imageloss_main<<<512, 256, 0, stream>>>(gt, pred, ws);
    imageloss_final<<<1, 1, 0, stream>>>(ws, out);
}

// Round 3
// 43.618 us; speedup vs baseline: 2.1206x; 1.0718x over previous
//
#include <hip/hip_runtime.h>

#define BIGV 1.0e6f

__device__ __forceinline__ float wave_max64(float v) {
    #pragma unroll
    for (int s = 32; s > 0; s >>= 1)
        v = fmaxf(v, __shfl_xor(v, s, 64));
    return v;
}

// One block per (b, h). 4 waves; wave c owns candidate offsets k = c + 4*l
// (k -> off: 0,+1,-1,+2,-2,... so |dx| is nondecreasing per wave).
// Rows are scanned lazily: row i is visited only if its sound lower bound
//   (1+|dx|) * rowmin(.)  can still beat some lane's current minimum.
__global__ __launch_bounds__(256) void imageloss_main(
    const float* __restrict__ gt, const float* __restrict__ pred,
    float* __restrict__ ws)
{
    __shared__ float gt_s[4096];
    __shared__ float pr_s[4096];
    __shared__ float rmg[64];
    __shared__ float rmp[64];
    __shared__ float red1[256];
    __shared__ float red2[256];

    const int blk = blockIdx.x;        // 0..511
    const int b   = blk >> 6;
    const int h   = blk & 63;
    const int tid = threadIdx.x;

    const float* __restrict__ gt_b = gt   + b * 4096;
    const float* __restrict__ pr_b = pred + b * 4096;

    // Stage images to LDS and fold in per-row minima (16 lanes per row).
    #pragma unroll
    for (int k = 0; k < 4; ++k) {
        int idx = tid + k * 256;               // float4 index, 16 per row
        float4 vg = ((const float4*)gt_b)[idx];
        float4 vp = ((const float4*)pr_b)[idx];
        ((float4*)gt_s)[idx] = vg;
        ((float4*)pr_s)[idx] = vp;
        float mg = fminf(fminf(vg.x, vg.y), fminf(vg.z, vg.w));
        float mp = fminf(fminf(vp.x, vp.y), fminf(vp.z, vp.w));
        #pragma unroll
        for (int s = 1; s < 16; s <<= 1) {
            mg = fminf(mg, __shfl_xor(mg, s, 64));
            mp = fminf(mp, __shfl_xor(mp, s, 64));
        }
        if ((tid & 15) == 0) {
            rmg[idx >> 4] = mg;
            rmp[idx >> 4] = mp;
        }
    }
    __syncthreads();

    const int w = tid & 63;
    const int c = tid >> 6;
    const float wf = (float)w;

    // Per-lane candidate table: lane l holds row for k = c + 4*l.
    const int l     = w;
    const int kcand = c + 4 * l;
    const int offc  = (kcand & 1) ? ((kcand + 1) >> 1) : -(kcand >> 1);
    const int rowc  = h + offc;
    const bool valid = (l < 32) && (kcand <= 126) && ((unsigned)rowc < 64u);
    float LB1 = 3.4e38f, LB2 = 3.4e38f;
    if (valid) {
        const int adx = offc < 0 ? -offc : offc;
        const float dpl = (float)(adx + 1);
        LB1 = dpl * rmp[rowc];   // lower bound for min over row (pred side)
        LB2 = dpl * rmg[rowc];   // lower bound (gt side)
    }
    unsigned long long remaining = __ballot(valid);

    float m1 = 3.4e38f;
    float m2 = 3.4e38f;

    while (remaining) {
        const float T1 = wave_max64(m1);
        const float T2 = wave_max64(m2);
        unsigned long long need =
            remaining & __ballot((LB1 < T1) || (LB2 < T2));
        if (!need) break;                       // no row can improve any lane
        const int lsel = (int)__builtin_ctzll(need);   // nearest useful row
        remaining &= ~(1ull << lsel);
        const int ksel = c + 4 * lsel;
        const int offs = (ksel & 1) ? ((ksel + 1) >> 1) : -(ksel >> 1);
        const int i    = h + offs;
        const float dx2 = (float)(offs * offs);

        const float4* __restrict__ pr4 = (const float4*)(pr_s + i * 64);
        const float4* __restrict__ gt4 = (const float4*)(gt_s + i * 64);
        #pragma unroll
        for (int j4 = 0; j4 < 16; ++j4) {
            float4 p4 = pr4[j4];   // uniform address -> broadcast ds_read_b128
            float4 g4 = gt4[j4];
            #pragma unroll
            for (int t = 0; t < 4; ++t) {
                float jf = (float)(j4 * 4 + t);
                float dy = wf - jf;
                float d  = __builtin_amdgcn_sqrtf(fmaf(dy, dy, dx2));
                float p  = (&p4.x)[t];
                float g  = (&g4.x)[t];
                m1 = fminf(m1, fmaf(d, p, p));   // (d+1)*p
                m2 = fminf(m2, fmaf(d, g, g));   // (d+1)*g
            }
        }
    }

    red1[tid] = m1;
    red2[tid] = m2;
    __syncthreads();

    if (tid < 64) {
        float a1 = fminf(fminf(red1[w], red1[64 + w]), fminf(red1[128 + w], red1[192 + w]));
        float a2 = fminf(fminf(red2[w], red2[64 + w]), fminf(red2[128 + w], red2[192 + w]));

        const float g = gt_s[h * 64 + w];
        const float p = pr_s[h * 64 + w];
        const float gth = g + (1.0f - g) * BIGV;
        const float pth = p + (1.0f - p) * BIGV;

        float c1 = gth * a1;   // contributes to min_dist
        float c2 = pth * a2;   // contributes to min_dist_inv
        float df = g - p;
        float sq = df * df;    // contributes to loss

        #pragma unroll
        for (int off = 32; off > 0; off >>= 1) {
            c1 += __shfl_down(c1, off, 64);
            c2 += __shfl_down(c2, off, 64);
            sq += __shfl_down(sq, off, 64);
        }
        if (w == 0) {
            atomicAdd(&ws[0], sq);
            atomicAdd(&ws[1], c1);
            atomicAdd(&ws[2], c2);
        }
    }
}

__global__ void imageloss_final(const float* __restrict__ ws, float* __restrict__ out)
{
    out[0] = ws[0] * (1.0f / 512.0f);
    out[1] = ws[1] * (1.0f / 32768.0f);
    out[2] = ws[2] * (1.0f / 32768.0f);
}

extern "C" void kernel_launch(void* const* d_in, const int* in_sizes, int n_in,
                              void* d_out, int out_size, void* d_ws, size_t ws_size,
                              hipStream_t stream)
{
    const float* gt   = (const float*)d_in[0];
    const float* pred = (const float*)d_in[1];
    float* out = (float*)d_out;
    float* ws  = (float*)d_ws;

    hipMemsetAsync(ws, 0, 3 * sizeof(float), stream);
    imageloss_main<<<512, 256, 0, stream>>>(gt, pred, ws);
    imageloss_final<<<1, 1, 0, stream>>>(ws, out);
}